// Round 10
// baseline (851.639 us; speedup 1.0000x reference)
//
#include <hip/hip_runtime.h>
#include <hip/hip_bf16.h>
#include <math.h>

typedef __attribute__((ext_vector_type(8))) short bf16x8;
typedef __attribute__((ext_vector_type(4))) float f32x4;

#define R_TOTAL 8
#define CIN     256
#define COUT    256
#define HH      128
#define WW      128
#define BB      4
#define MTOT    (COUT * R_TOTAL)   // 2048
#define KTAPS   9

#define ROWSZ 4160                 // one X row slot: 130 cols x 32 ch (elems)
#define ABUF  (128 * 32)           // 4096 elems per A buffer (8 KB)

// ---------------------------------------------------------------------------
// async global->LDS, 16B per lane (lane l lands at base + l*16).
// ---------------------------------------------------------------------------
__device__ __forceinline__ void g2l16(void* lds, const void* g) {
    __builtin_amdgcn_global_load_lds(
        (const __attribute__((address_space(1))) unsigned int*)g,
        (__attribute__((address_space(3))) unsigned int*)lds,
        16, 0, 0);
}

// ---------------------------------------------------------------------------
// x (B,C,H,W) fp32 -> xb (B,H,W,C) bf16 (+ one appended zero row).
// ---------------------------------------------------------------------------
__global__ __launch_bounds__(256)
void to_nhwc_bf16(const float* __restrict__ x, __hip_bfloat16* __restrict__ xb) {
    __shared__ __hip_bfloat16 t[32][33];
    const int b  = blockIdx.z;
    const int c0 = blockIdx.y * 32;
    const int p0 = blockIdx.x * 32;
    const int tx = threadIdx.x & 31;
    const int ty = threadIdx.x >> 5;
    const float* xp = x + (size_t)b * CIN * (HH * WW);
    #pragma unroll
    for (int j = 0; j < 4; ++j) {
        int c = ty * 4 + j;
        t[c][tx] = __float2bfloat16(xp[(size_t)(c0 + c) * (HH * WW) + p0 + tx]);
    }
    __syncthreads();
    __hip_bfloat16* op = xb + ((size_t)b * (HH * WW) + p0) * CIN + c0;
    #pragma unroll
    for (int j = 0; j < 4; ++j) {
        int p = ty * 4 + j;
        op[(size_t)p * CIN + tx] = t[tx][p];
    }
}

__global__ __launch_bounds__(256)
void zero_guard_row(__hip_bfloat16* __restrict__ xb) {
    size_t base = (size_t)BB * HH * WW * CIN;
    int i = blockIdx.x * 256 + threadIdx.x;
    xb[base + i] = __float2bfloat16(0.0f);
}

// ---------------------------------------------------------------------------
// Rotate weights (fp32 math == jax affine_grid/grid_sample, align_corners=F,
// zero pad) -> rwb[m][tap][i] bf16, m = o*8 + r.
// ---------------------------------------------------------------------------
__global__ __launch_bounds__(256)
void rotate_weights_bf16(const float* __restrict__ w, __hip_bfloat16* __restrict__ rwb) {
    const int i = threadIdx.x;
    const int m = blockIdx.x;
    const int o = m >> 3, r = m & 7;

    float ang = 6.283185307179586f * (float)r / 8.0f;
    float cs = cosf(ang), sn = sinf(ang);

    const float* wp = w + ((size_t)o * CIN + i) * 9;
    __hip_bfloat16* op = rwb + (size_t)m * (KTAPS * CIN) + i;

    #pragma unroll
    for (int ky = 0; ky < 3; ++ky) {
        #pragma unroll
        for (int kx = 0; kx < 3; ++kx) {
            float yg = (2.0f * (float)ky + 1.0f) / 3.0f - 1.0f;
            float xg = (2.0f * (float)kx + 1.0f) / 3.0f - 1.0f;
            float xsf = cs * xg - sn * yg;
            float ysf = sn * xg + cs * yg;
            float ix = ((xsf + 1.0f) * 3.0f - 1.0f) * 0.5f;
            float iy = ((ysf + 1.0f) * 3.0f - 1.0f) * 0.5f;
            float ix0f = floorf(ix), iy0f = floorf(iy);
            float wx1 = ix - ix0f,  wy1 = iy - iy0f;
            float wx0 = 1.0f - wx1, wy0 = 1.0f - wy1;
            int ix0 = (int)ix0f, iy0 = (int)iy0f;
            int ix1 = ix0 + 1,   iy1 = iy0 + 1;
            float acc = 0.0f;
            if (iy0 >= 0 && iy0 < 3 && ix0 >= 0 && ix0 < 3) acc += wp[iy0*3+ix0] * (wy0*wx0);
            if (iy0 >= 0 && iy0 < 3 && ix1 >= 0 && ix1 < 3) acc += wp[iy0*3+ix1] * (wy0*wx1);
            if (iy1 >= 0 && iy1 < 3 && ix0 >= 0 && ix0 < 3) acc += wp[iy1*3+ix0] * (wy1*wx0);
            if (iy1 >= 0 && iy1 < 3 && ix1 >= 0 && ix1 < 3) acc += wp[iy1*3+ix1] * (wy1*wx1);
            op[(ky * 3 + kx) * CIN] = __float2bfloat16(acc);
        }
    }
}

// ---------------------------------------------------------------------------
// Main MFMA conv: 256 threads = 4 waves (2M x 2N), block tile 128M x 256N
// (TWO image rows; wave tile 64M x 128N = one full row -> 12 ds_read_b128
// per 32 MFMA = 42.7 FLOP/LDS-byte). K = 8 chunks(32ch) x 9 taps.
// X: rolling 5-slot row buffer, slot(r,c) = (4c+r) mod 5; one row staged per
// 2 taps (1 g2l/wave/tap) into a slot freed by the barrier schedule.
// A: 3-slot buffer (slot = tap%3), prefetch distance 2, 2 g2l/wave/tap.
// Counted vmcnt, one raw s_barrier per tap; staging is issued AFTER the
// barrier (WAR on recycled slots provably race-free). LDS 64.6 KB ->
// 2 blocks/CU (8 waves, 2/SIMD).
// ---------------------------------------------------------------------------
__global__ __launch_bounds__(256)
void rotconv_mfma_kernel(const __hip_bfloat16* __restrict__ xb,
                         const __hip_bfloat16* __restrict__ rwb,
                         float* __restrict__ out) {
    const int tid  = threadIdx.x;
    const int lane = tid & 63;
    const int w    = tid >> 6;        // 0..3
    const int wm   = w >> 1;          // 0..1
    const int wn   = w & 1;           // 0..1  (owns output row y0+wn)
    const int q    = lane >> 4, lr = lane & 15;

    // bijective XCD swizzle (4096 % 8 == 0), m-major for A-panel L2 reuse
    const int bid = (blockIdx.x & 7) * 512 + (blockIdx.x >> 3);
    const int mt  = bid >> 8;         // 0..15
    const int nt  = bid & 255;        // 0..255
    const int b   = nt >> 6;          // 0..3
    const int y0  = (nt & 63) * 2;    // 0..126
    const int m0  = mt << 7;

    __shared__ __align__(16) __hip_bfloat16 xs[5 * ROWSZ];
    __shared__ __align__(16) __hip_bfloat16 As[3 * ABUF];

    // zero halo columns (colL = 0 and 129) of all 5 slots (stay zero forever)
    for (int j = tid; j < 5 * 64; j += 256) {
        int slot = j >> 6;
        int rem  = j & 63;
        int colL = (rem >> 5) ? 129 : 0;
        int ch   = rem & 31;
        xs[slot * ROWSZ + colL * 32 + ch] = __float2bfloat16(0.0f);
    }

    // ---- A read offsets (element units), slot-swizzled ----
    int aOff[4];
    #pragma unroll
    for (int mi = 0; mi < 4; ++mi) {
        int row = wm * 64 + mi * 16 + lr;
        aOff[mi] = row * 32 + 8 * (q ^ ((row >> 1) & 3));
    }
    // ---- B read offsets: colL = ni*16 + lr + kx; swizzle invariant mod 16 ----
    int bOff0[3];
    #pragma unroll
    for (int kx = 0; kx < 3; ++kx) {
        int colL = lr + kx;
        bOff0[kx] = colL * 32 + 8 * (q ^ ((colL >> 1) & 3));
    }

    // ---- A staging: wave w covers rows w*32..w*32+31 (2 g2l per wave) ----
    const int arow0 = w * 32 + (lane >> 2);
    const int arow1 = w * 32 + 16 + (lane >> 2);
    const int dstA0 = (w * 32) * 32;                    // wave-uniform
    const int dstA1 = (w * 32 + 16) * 32;
    const __hip_bfloat16* srcA0 =
        rwb + (size_t)(m0 + arow0) * (KTAPS * CIN) + 8 * ((lane & 3) ^ ((arow0 >> 1) & 3));
    const __hip_bfloat16* srcA1 =
        rwb + (size_t)(m0 + arow1) * (KTAPS * CIN) + 8 * ((lane & 3) ^ ((arow1 >> 1) & 3));

    // ---- X staging: 4 window rows x 2 parts/wave (part j = w and w+4) ----
    const __hip_bfloat16* srcX[8];
    #pragma unroll
    for (int r = 0; r < 4; ++r) {
        int gy = y0 - 1 + r;
        size_t rowIdx = ((unsigned)gy < (unsigned)HH) ? (size_t)(b * HH + gy)
                                                      : (size_t)(BB * HH);
        #pragma unroll
        for (int p = 0; p < 2; ++p) {
            int jp = w + 4 * p;
            int gx = jp * 16 + (lane >> 2);
            int colL = gx + 1;
            srcX[r * 2 + p] = xb + (rowIdx * WW + gx) * CIN
                                 + 8 * ((lane & 3) ^ ((colL >> 1) & 3));
        }
    }
    const int dstXp0 = 32 + w * 512;          // element offset within a slot
    const int dstXp1 = 32 + (w + 4) * 512;

    f32x4 acc[4][8];
    #pragma unroll
    for (int mi = 0; mi < 4; ++mi)
        #pragma unroll
        for (int ni = 0; ni < 8; ++ni) {
            f32x4 z = {0.f, 0.f, 0.f, 0.f};
            acc[mi][ni] = z;
        }

    __syncthreads();   // halo zeros visible

    // prologue: X rows r0..r3 -> slots 0..3 (chunk 0), A(0)->slot0, A(1)->slot1
    #pragma unroll
    for (int r = 0; r < 4; ++r) {
        g2l16(xs + r * ROWSZ + dstXp0, srcX[r * 2 + 0]);
        g2l16(xs + r * ROWSZ + dstXp1, srcX[r * 2 + 1]);
    }
    g2l16(As + dstA0, srcA0);
    g2l16(As + dstA1, srcA1);
    g2l16(As + ABUF + dstA0, srcA0 + CIN);
    g2l16(As + ABUF + dstA1, srcA1 + CIN);
    asm volatile("s_waitcnt vmcnt(0)" ::: "memory");
    __syncthreads();

    int cOff  = 0;   // c*32 channel offset
    int base5 = 0;   // (4c) mod 5

// ---- one tap: counted wait, barrier, THEN stage A(t+2) [+ one X row part],
//      ds-read frags, 32 MFMA in 2 half-clusters. All indices compile-time.
#define TAP(P, NW, DOA, DOX, XIDX, XSLOT, XOFF)                                \
  {                                                                            \
    asm volatile("s_waitcnt vmcnt(%0)" :: "i"(NW) : "memory");                 \
    asm volatile("s_barrier" ::: "memory");                                    \
    if (DOA) {                                                                 \
      __hip_bfloat16* ab = As + (((P) + 2) % 3) * ABUF;                        \
      const int aofs = (((P) + 2) % 9) * CIN + (((P) + 2) / 9) * 32 + cOff;    \
      g2l16(ab + dstA0, srcA0 + aofs);                                         \
      g2l16(ab + dstA1, srcA1 + aofs);                                         \
    }                                                                          \
    if (DOX) {                                                                 \
      g2l16(xs + (XSLOT) * ROWSZ + (((P) & 1) ? dstXp1 : dstXp0),              \
            srcX[XIDX] + (XOFF));                                              \
    }                                                                          \
    {                                                                          \
      const __hip_bfloat16* ar = As + ((P) % 3) * ABUF;                        \
      const __hip_bfloat16* br =                                               \
          ((P) / 3 == 0 ? xrow0 : (P) / 3 == 1 ? xrow1 : xrow2)                \
          + bOff0[(P) % 3];                                                    \
      bf16x8 af[4];                                                            \
      _Pragma("unroll")                                                        \
      for (int mi = 0; mi < 4; ++mi) af[mi] = *(const bf16x8*)(ar + aOff[mi]); \
      _Pragma("unroll")                                                        \
      for (int h = 0; h < 2; ++h) {                                            \
        bf16x8 bv[4];                                                          \
        _Pragma("unroll")                                                      \
        for (int nj = 0; nj < 4; ++nj)                                         \
            bv[nj] = *(const bf16x8*)(br + (h * 4 + nj) * 512);                \
        __builtin_amdgcn_s_setprio(1);                                         \
        _Pragma("unroll")                                                      \
        for (int mi = 0; mi < 4; ++mi)                                         \
          _Pragma("unroll")                                                    \
          for (int nj = 0; nj < 4; ++nj)                                       \
            acc[mi][h * 4 + nj] = __builtin_amdgcn_mfma_f32_16x16x32_bf16(     \
                af[mi], bv[nj], acc[mi][h * 4 + nj], 0, 0, 0);                 \
        __builtin_amdgcn_s_setprio(0);                                         \
      }                                                                        \
    }                                                                          \
  }

#define WRAP5(v) ((v) >= 5 ? (v) - 5 : (v))

    // ---- chunk 0 (X rows for c0 prologue-staged; stage r0..r2 of c1) ----
    {
        const int rbw = base5 + wn;
        const int sky0 = WRAP5(rbw), sky1 = WRAP5(rbw + 1), sky2 = WRAP5(rbw + 2);
        const __hip_bfloat16* xrow0 = xs + sky0 * ROWSZ;
        const __hip_bfloat16* xrow1 = xs + sky1 * ROWSZ;
        const __hip_bfloat16* xrow2 = xs + sky2 * ROWSZ;
        const int s23 = WRAP5(base5 + 4);
        const int s45 = base5;
        const int s67 = WRAP5(base5 + 1);
        TAP(0, 0, 1, 0, 0, 0, 0)
        TAP(1, 2, 1, 0, 0, 0, 0)
        TAP(2, 2, 1, 1, 0, s23, 32)
        TAP(3, 3, 1, 1, 1, s23, 32)
        TAP(4, 4, 1, 1, 2, s45, 32)
        TAP(5, 4, 1, 1, 3, s45, 32)
        TAP(6, 4, 1, 1, 4, s67, 32)
        TAP(7, 4, 1, 1, 5, s67, 32)
        TAP(8, 4, 1, 0, 0, 0, 0)
    }

    // ---- steady chunks 1..6 ----
    for (int c = 1; c <= 6; ++c) {
        cOff += 32;
        base5 = (base5 == 0) ? 4 : base5 - 1;
        const int rbw = base5 + wn;
        const int sky0 = WRAP5(rbw), sky1 = WRAP5(rbw + 1), sky2 = WRAP5(rbw + 2);
        const __hip_bfloat16* xrow0 = xs + sky0 * ROWSZ;
        const __hip_bfloat16* xrow1 = xs + sky1 * ROWSZ;
        const __hip_bfloat16* xrow2 = xs + sky2 * ROWSZ;
        const int s01 = WRAP5(base5 + 3);
        const int s23 = WRAP5(base5 + 4);
        const int s45 = base5;
        const int s67 = WRAP5(base5 + 1);
        TAP(0, 3, 1, 1, 6, s01, cOff)
        TAP(1, 3, 1, 1, 7, s01, cOff)
        TAP(2, 4, 1, 1, 0, s23, cOff + 32)
        TAP(3, 4, 1, 1, 1, s23, cOff + 32)
        TAP(4, 4, 1, 1, 2, s45, cOff + 32)
        TAP(5, 4, 1, 1, 3, s45, cOff + 32)
        TAP(6, 4, 1, 1, 4, s67, cOff + 32)
        TAP(7, 4, 1, 1, 5, s67, cOff + 32)
        TAP(8, 4, 1, 0, 0, 0, 0)
    }

    // ---- tail chunk 7 ----
    {
        cOff += 32;   // 224
        base5 = (base5 == 0) ? 4 : base5 - 1;   // 3
        const int rbw = base5 + wn;
        const int sky0 = WRAP5(rbw), sky1 = WRAP5(rbw + 1), sky2 = WRAP5(rbw + 2);
        const __hip_bfloat16* xrow0 = xs + sky0 * ROWSZ;
        const __hip_bfloat16* xrow1 = xs + sky1 * ROWSZ;
        const __hip_bfloat16* xrow2 = xs + sky2 * ROWSZ;
        const int s01 = WRAP5(base5 + 3);
        TAP(0, 3, 1, 1, 6, s01, cOff)
        TAP(1, 3, 1, 1, 7, s01, cOff)
        TAP(2, 4, 1, 0, 0, 0, 0)
        TAP(3, 3, 1, 0, 0, 0, 0)
        TAP(4, 2, 1, 0, 0, 0, 0)
        TAP(5, 2, 1, 0, 0, 0, 0)
        TAP(6, 2, 1, 0, 0, 0, 0)
        TAP(7, 2, 0, 0, 0, 0, 0)
        TAP(8, 0, 0, 0, 0, 0, 0)
    }

#undef TAP
#undef WRAP5

    // epilogue: max over 8 rotations (4 regs + quarter-swap), write fp32
    const int oBase = (m0 + wm * 64) >> 3;
    const int yOut  = y0 + wn;
    #pragma unroll
    for (int mi = 0; mi < 4; ++mi) {
        #pragma unroll
        for (int ni = 0; ni < 8; ++ni) {
            f32x4 a4 = acc[mi][ni];
            float v = fmaxf(fmaxf(a4[0], a4[1]), fmaxf(a4[2], a4[3]));
            v = fmaxf(v, __shfl_xor(v, 16));
            if ((q & 1) == 0) {
                int o = oBase + mi * 2 + (q >> 1);
                int colc = ni * 16 + lr;
                out[(((size_t)(b * COUT + o)) * HH + yOut) * WW + colc] = v;
            }
        }
    }
}

// ===========================================================================
// Fallback fp32 path (round-0, known-correct) in case ws is too small.
// ===========================================================================
__global__ void rotate_weights_kernel(const float* __restrict__ w,
                                      float* __restrict__ rw,
                                      int r0, int rcount) {
    int idx = blockIdx.x * blockDim.x + threadIdx.x;
    int total = COUT * CIN * rcount;
    if (idx >= total) return;
    int rr = idx % rcount;
    int ii = (idx / rcount) % CIN;
    int oo = idx / (rcount * CIN);
    int r  = r0 + rr;
    float ang = 6.283185307179586f * (float)r / 8.0f;
    float cs = cosf(ang), sn = sinf(ang);
    const float* wp = w  + ((size_t)oo * CIN + ii) * 9;
    float*       op = rw + (((size_t)oo * CIN + ii) * rcount + rr) * 9;
    #pragma unroll
    for (int ky = 0; ky < 3; ++ky)
        #pragma unroll
        for (int kx = 0; kx < 3; ++kx) {
            float yg = (2.0f * ky + 1.0f) / 3.0f - 1.0f;
            float xg = (2.0f * kx + 1.0f) / 3.0f - 1.0f;
            float xsf = cs * xg - sn * yg;
            float ysf = sn * xg + cs * yg;
            float ix = ((xsf + 1.0f) * 3.0f - 1.0f) * 0.5f;
            float iy = ((ysf + 1.0f) * 3.0f - 1.0f) * 0.5f;
            float ix0f = floorf(ix), iy0f = floorf(iy);
            float wx1 = ix - ix0f,  wy1 = iy - iy0f;
            float wx0 = 1.0f - wx1, wy0 = 1.0f - wy1;
            int ix0 = (int)ix0f, iy0 = (int)iy0f;
            int ix1 = ix0 + 1,   iy1 = iy0 + 1;
            float acc = 0.0f;
            if (iy0 >= 0 && iy0 < 3 && ix0 >= 0 && ix0 < 3) acc += wp[iy0*3+ix0]*(wy0*wx0);
            if (iy0 >= 0 && iy0 < 3 && ix1 >= 0 && ix1 < 3) acc += wp[iy0*3+ix1]*(wy0*wx1);
            if (iy1 >= 0 && iy1 < 3 && ix0 >= 0 && ix0 < 3) acc += wp[iy1*3+ix0]*(wy1*wx0);
            if (iy1 >= 0 && iy1 < 3 && ix1 >= 0 && ix1 < 3) acc += wp[iy1*3+ix1]*(wy1*wx1);
            op[ky * 3 + kx] = acc;
        }
}

template <int RCOUNT>
__global__ __launch_bounds__(256)
void rotconv_max_kernel(const float* __restrict__ x,
                        const float* __restrict__ rw,
                        float* __restrict__ out,
                        int first) {
    const int tid = threadIdx.x;
    const int tx = tid & 15;
    const int ty = tid >> 4;
    const int x0 = blockIdx.x * 32;
    const int y0 = blockIdx.y * 32;
    const int o  = blockIdx.z % COUT;
    const int b  = blockIdx.z / COUT;
    __shared__ float xsm[34][36];
    float acc[RCOUNT][2][2];
    #pragma unroll
    for (int r = 0; r < RCOUNT; ++r)
        #pragma unroll
        for (int py = 0; py < 2; ++py)
            #pragma unroll
            for (int px = 0; px < 2; ++px) acc[r][py][px] = 0.0f;
    for (int i = 0; i < CIN; ++i) {
        __syncthreads();
        const float* xp = x + ((size_t)(b * CIN + i)) * (HH * WW);
        for (int idx = tid; idx < 34 * 34; idx += 256) {
            int row = idx / 34, col = idx - row * 34;
            int gy = y0 - 1 + row, gx = x0 - 1 + col;
            float v = 0.0f;
            if (gy >= 0 && gy < HH && gx >= 0 && gx < WW) v = xp[gy * WW + gx];
            xsm[row][col] = v;
        }
        __syncthreads();
        float xv[4][4];
        #pragma unroll
        for (int ry = 0; ry < 4; ++ry)
            #pragma unroll
            for (int cx = 0; cx < 4; ++cx) xv[ry][cx] = xsm[ty*2+ry][tx*2+cx];
        const float* wp = rw + ((size_t)(o * CIN + i)) * (RCOUNT * 9);
        #pragma unroll
        for (int r = 0; r < RCOUNT; ++r) {
            float wv[9];
            #pragma unroll
            for (int t2 = 0; t2 < 9; ++t2) wv[t2] = wp[r * 9 + t2];
            #pragma unroll
            for (int py = 0; py < 2; ++py)
                #pragma unroll
                for (int px = 0; px < 2; ++px) {
                    float a = acc[r][py][px];
                    #pragma unroll
                    for (int ky = 0; ky < 3; ++ky)
                        #pragma unroll
                        for (int kx = 0; kx < 3; ++kx)
                            a += xv[py+ky][px+kx] * wv[ky*3+kx];
                    acc[r][py][px] = a;
                }
        }
    }
    #pragma unroll
    for (int py = 0; py < 2; ++py)
        #pragma unroll
        for (int px = 0; px < 2; ++px) {
            float m = acc[0][py][px];
            #pragma unroll
            for (int r = 1; r < RCOUNT; ++r) m = fmaxf(m, acc[r][py][px]);
            int oy = y0 + ty * 2 + py;
            int ox = x0 + tx * 2 + px;
            float* op = out + (((size_t)(b * COUT + o)) * HH + oy) * WW + ox;
            if (first) *op = m;
            else       *op = fmaxf(*op, m);
        }
}

// ===========================================================================
extern "C" void kernel_launch(void* const* d_in, const int* in_sizes, int n_in,
                              void* d_out, int out_size, void* d_ws, size_t ws_size,
                              hipStream_t stream) {
    const float* x = (const float*)d_in[0];
    const float* w = (const float*)d_in[1];
    float* out = (float*)d_out;

    const size_t xbBytes = ((size_t)BB * HH * WW + WW) * CIN * sizeof(__hip_bfloat16); // +1 zero row
    const size_t rwBytes = (size_t)MTOT * KTAPS * CIN * sizeof(__hip_bfloat16);

    if (ws_size >= xbBytes + rwBytes) {
        __hip_bfloat16* xbuf = (__hip_bfloat16*)d_ws;
        __hip_bfloat16* rwb  = (__hip_bfloat16*)((char*)d_ws + xbBytes);

        to_nhwc_bf16<<<dim3((HH * WW) / 32, CIN / 32, BB), 256, 0, stream>>>(x, xbuf);
        zero_guard_row<<<(WW * CIN) / 256, 256, 0, stream>>>(xbuf);
        rotate_weights_bf16<<<MTOT, 256, 0, stream>>>(w, rwb);
        rotconv_mfma_kernel<<<4096, 256, 0, stream>>>(xbuf, rwb, out);
        return;
    }

    // ---- fallback fp32 path ----
    float* rw = (float*)d_ws;
    int chunk = 8;
    while (chunk > 1 && (size_t)COUT * CIN * chunk * 9 * sizeof(float) > ws_size)
        chunk >>= 1;
    int first = 1;
    for (int r0 = 0; r0 < R_TOTAL; r0 += chunk) {
        int rc = chunk;
        int total = COUT * CIN * rc;
        rotate_weights_kernel<<<(total + 255) / 256, 256, 0, stream>>>(w, rw, r0, rc);
        dim3 grid(WW / 32, HH / 32, BB * COUT);
        switch (rc) {
            case 8: rotconv_max_kernel<8><<<grid, 256, 0, stream>>>(x, rw, out, first); break;
            case 4: rotconv_max_kernel<4><<<grid, 256, 0, stream>>>(x, rw, out, first); break;
            case 2: rotconv_max_kernel<2><<<grid, 256, 0, stream>>>(x, rw, out, first); break;
            default: rotconv_max_kernel<1><<<grid, 256, 0, stream>>>(x, rw, out, first); break;
        }
        first = 0;
    }
}

// Round 11
// 658.476 us; speedup vs baseline: 1.2933x; 1.2933x over previous
//
#include <hip/hip_runtime.h>
#include <hip/hip_bf16.h>
#include <math.h>

typedef __attribute__((ext_vector_type(8))) short bf16x8;
typedef __attribute__((ext_vector_type(4))) float f32x4;

#define R_TOTAL 8
#define CIN     256
#define COUT    256
#define HH      128
#define WW      128
#define BB      4
#define MTOT    (COUT * R_TOTAL)   // 2048
#define KTAPS   9

#define XSZ   (3 * 130 * 32)       // 12480 elems per X buffer (24.375 KB)
#define ABUF  (128 * 32)           // 4096 elems per A buffer (8 KB)

// ---------------------------------------------------------------------------
// async global->LDS, 16B per lane (lane l lands at base + l*16).
// ---------------------------------------------------------------------------
__device__ __forceinline__ void g2l16(void* lds, const void* g) {
    __builtin_amdgcn_global_load_lds(
        (const __attribute__((address_space(1))) unsigned int*)g,
        (__attribute__((address_space(3))) unsigned int*)lds,
        16, 0, 0);
}

// ---------------------------------------------------------------------------
// x (B,C,H,W) fp32 -> xb (B,H,W,C) bf16 (+ one appended zero row).
// ---------------------------------------------------------------------------
__global__ __launch_bounds__(256)
void to_nhwc_bf16(const float* __restrict__ x, __hip_bfloat16* __restrict__ xb) {
    __shared__ __hip_bfloat16 t[32][33];
    const int b  = blockIdx.z;
    const int c0 = blockIdx.y * 32;
    const int p0 = blockIdx.x * 32;
    const int tx = threadIdx.x & 31;
    const int ty = threadIdx.x >> 5;
    const float* xp = x + (size_t)b * CIN * (HH * WW);
    #pragma unroll
    for (int j = 0; j < 4; ++j) {
        int c = ty * 4 + j;
        t[c][tx] = __float2bfloat16(xp[(size_t)(c0 + c) * (HH * WW) + p0 + tx]);
    }
    __syncthreads();
    __hip_bfloat16* op = xb + ((size_t)b * (HH * WW) + p0) * CIN + c0;
    #pragma unroll
    for (int j = 0; j < 4; ++j) {
        int p = ty * 4 + j;
        op[(size_t)p * CIN + tx] = t[tx][p];
    }
}

__global__ __launch_bounds__(256)
void zero_guard_row(__hip_bfloat16* __restrict__ xb) {
    size_t base = (size_t)BB * HH * WW * CIN;
    int i = blockIdx.x * 256 + threadIdx.x;
    xb[base + i] = __float2bfloat16(0.0f);
}

// ---------------------------------------------------------------------------
// Rotate weights (fp32 math == jax affine_grid/grid_sample, align_corners=F,
// zero pad) -> rwb[m][tap][i] bf16, m = o*8 + r.
// ---------------------------------------------------------------------------
__global__ __launch_bounds__(256)
void rotate_weights_bf16(const float* __restrict__ w, __hip_bfloat16* __restrict__ rwb) {
    const int i = threadIdx.x;
    const int m = blockIdx.x;
    const int o = m >> 3, r = m & 7;

    float ang = 6.283185307179586f * (float)r / 8.0f;
    float cs = cosf(ang), sn = sinf(ang);

    const float* wp = w + ((size_t)o * CIN + i) * 9;
    __hip_bfloat16* op = rwb + (size_t)m * (KTAPS * CIN) + i;

    #pragma unroll
    for (int ky = 0; ky < 3; ++ky) {
        #pragma unroll
        for (int kx = 0; kx < 3; ++kx) {
            float yg = (2.0f * (float)ky + 1.0f) / 3.0f - 1.0f;
            float xg = (2.0f * (float)kx + 1.0f) / 3.0f - 1.0f;
            float xsf = cs * xg - sn * yg;
            float ysf = sn * xg + cs * yg;
            float ix = ((xsf + 1.0f) * 3.0f - 1.0f) * 0.5f;
            float iy = ((ysf + 1.0f) * 3.0f - 1.0f) * 0.5f;
            float ix0f = floorf(ix), iy0f = floorf(iy);
            float wx1 = ix - ix0f,  wy1 = iy - iy0f;
            float wx0 = 1.0f - wx1, wy0 = 1.0f - wy1;
            int ix0 = (int)ix0f, iy0 = (int)iy0f;
            int ix1 = ix0 + 1,   iy1 = iy0 + 1;
            float acc = 0.0f;
            if (iy0 >= 0 && iy0 < 3 && ix0 >= 0 && ix0 < 3) acc += wp[iy0*3+ix0] * (wy0*wx0);
            if (iy0 >= 0 && iy0 < 3 && ix1 >= 0 && ix1 < 3) acc += wp[iy0*3+ix1] * (wy0*wx1);
            if (iy1 >= 0 && iy1 < 3 && ix0 >= 0 && ix0 < 3) acc += wp[iy1*3+ix0] * (wy1*wx0);
            if (iy1 >= 0 && iy1 < 3 && ix1 >= 0 && ix1 < 3) acc += wp[iy1*3+ix1] * (wy1*wx1);
            op[(ky * 3 + kx) * CIN] = __float2bfloat16(acc);
        }
    }
}

// ---------------------------------------------------------------------------
// Main MFMA conv: 256 threads = 4 waves (2M x 2N), block tile 128M x 128N
// (one image row), wave tile 64x64. K = 8 chunks(32ch) x 9 taps.
// R11 schedule (fix of R9's 1-tap-slack stall):
//  - Frag pipelining: tap t ds-reads tap-(t+1) fragments into the alternate
//    register set; tap-t MFMAs consume last phase's regs (no lgkm on path).
//  - A: 3 LDS slots, issue distance 3 (A(t+3) -> slot t%3, which was freed
//    when its frags were register-read at tap t-1). 2 full taps of latency
//    cover for every A tile.
//  - X: 3-row window double-buffered; parts 0..5 of chunk c+1 issued at taps
//    0..5 (3..8 taps of cover).
//  - Tap order: counted wait -> raw barrier -> issue loads -> ds_read -> MFMA.
//    NW(t) = issues(t-1) (FIFO in-order retire): steady [2,3,3,3,3,3,3,2,2].
// LDS 74.5 KB -> 2 blocks/CU (8 waves, 2/SIMD).
// ---------------------------------------------------------------------------
__global__ __launch_bounds__(256)
void rotconv_mfma_kernel(const __hip_bfloat16* __restrict__ xb,
                         const __hip_bfloat16* __restrict__ rwb,
                         float* __restrict__ out) {
    const int tid  = threadIdx.x;
    const int lane = tid & 63;
    const int w    = tid >> 6;        // 0..3
    const int wm   = w >> 1;          // 0..1
    const int wn   = w & 1;           // 0..1
    const int q    = lane >> 4, lr = lane & 15;

    // bijective XCD swizzle (8192 % 8 == 0), m-major for A-panel L2 reuse
    const int bid = (blockIdx.x & 7) * 1024 + (blockIdx.x >> 3);
    const int mt  = bid >> 9;         // 0..15
    const int nt  = bid & 511;        // 0..511
    const int b   = nt >> 7;          // 0..3
    const int y0  = nt & 127;         // 0..127
    const int m0  = mt << 7;

    __shared__ __align__(16) __hip_bfloat16 xs[2 * XSZ];
    __shared__ __align__(16) __hip_bfloat16 As[3 * ABUF];

    // zero halo columns (colL = 0 and 129): 2 bufs x 3 rows x 2 cols x 32 ch
    for (int j = tid; j < 384; j += 256) {
        int bufi = j / 192;
        int rem  = j % 192;
        int row = rem / 64; int colsel = (rem >> 5) & 1; int ch = rem & 31;
        int colL = colsel ? 129 : 0;
        xs[bufi * XSZ + (row * 130 + colL) * 32 + ch] = __float2bfloat16(0.0f);
    }

    // ---- A read offsets (element units), slot-swizzled ----
    int aOff[4];
    #pragma unroll
    for (int mi = 0; mi < 4; ++mi) {
        int row = wm * 64 + mi * 16 + lr;
        aOff[mi] = row * 32 + 8 * (q ^ ((row >> 1) & 3));
    }
    // ---- B read offsets: col = wn*64 + ni*16 + lr + kx (row base at use) ----
    int bOff[4][3];
    #pragma unroll
    for (int ni = 0; ni < 4; ++ni)
        #pragma unroll
        for (int kx = 0; kx < 3; ++kx) {
            int colL = wn * 64 + ni * 16 + lr + kx;     // 0..129
            bOff[ni][kx] = colL * 32 + 8 * (q ^ ((colL >> 1) & 3));
        }

    // ---- A staging: wave w covers rows w*32..w*32+31 (2 g2l per wave) ----
    const int arow0 = w * 32 + (lane >> 2);
    const int arow1 = w * 32 + 16 + (lane >> 2);
    const int dstA0 = (w * 32) * 32;                    // wave-uniform
    const int dstA1 = (w * 32 + 16) * 32;
    const __hip_bfloat16* srcA0 =
        rwb + (size_t)(m0 + arow0) * (KTAPS * CIN) + 8 * ((lane & 3) ^ ((arow0 >> 1) & 3));
    const __hip_bfloat16* srcA1 =
        rwb + (size_t)(m0 + arow1) * (KTAPS * CIN) + 8 * ((lane & 3) ^ ((arow1 >> 1) & 3));

    // ---- X staging: 6 parts/wave cover 3 rows x 8 col-groups ----
    const __hip_bfloat16* srcX[6];
    int dstX[6];
    #pragma unroll
    for (int j = 0; j < 6; ++j) {
        int id  = j * 4 + w;                 // 0..23
        int row = id >> 3;                   // 0..2
        int cg  = (id & 7) * 16;
        int gy  = y0 - 1 + row;
        size_t rowIdx = ((unsigned)gy < (unsigned)HH) ? (size_t)(b * HH + gy)
                                                      : (size_t)(BB * HH);
        int gx = cg + (lane >> 2);
        int colL = gx + 1;
        dstX[j] = (row * 130 + 1 + cg) * 32;            // wave-uniform
        srcX[j] = xb + (rowIdx * WW + gx) * CIN + 8 * ((lane & 3) ^ ((colL >> 1) & 3));
    }

    f32x4 acc[4][4];
    #pragma unroll
    for (int mi = 0; mi < 4; ++mi)
        #pragma unroll
        for (int ni = 0; ni < 4; ++ni) {
            f32x4 z = {0.f, 0.f, 0.f, 0.f};
            acc[mi][ni] = z;
        }

    __syncthreads();   // halo zeros visible

    // prologue: X(chunk0) parts 0..5; A(0..2) -> slots 0..2; full drain.
    #pragma unroll
    for (int j = 0; j < 6; ++j) g2l16(xs + dstX[j], srcX[j]);
    g2l16(As + 0 * ABUF + dstA0, srcA0 + 0 * CIN);
    g2l16(As + 0 * ABUF + dstA1, srcA1 + 0 * CIN);
    g2l16(As + 1 * ABUF + dstA0, srcA0 + 1 * CIN);
    g2l16(As + 1 * ABUF + dstA1, srcA1 + 1 * CIN);
    g2l16(As + 2 * ABUF + dstA0, srcA0 + 2 * CIN);
    g2l16(As + 2 * ABUF + dstA1, srcA1 + 2 * CIN);
    asm volatile("s_waitcnt vmcnt(0)" ::: "memory");
    __syncthreads();

    // fragment register double-buffer (static names -> no scratch)
    bf16x8 af0[4], bv0[4], af1[4], bv1[4];
    {   // frags for global tap 0: A slot 0, X buf 0, row 0, kx 0 -> set 0
        const __hip_bfloat16* ar = As;
        const __hip_bfloat16* br = xs;
        #pragma unroll
        for (int mi = 0; mi < 4; ++mi) af0[mi] = *(const bf16x8*)(ar + aOff[mi]);
        #pragma unroll
        for (int ni = 0; ni < 4; ++ni) bv0[ni] = *(const bf16x8*)(br + bOff[ni][0]);
    }

// ---- one tap (chunk c, tap P): wait(NW) -> barrier -> issue A(g+3) into
//      slot P%3 [+ X part P of chunk c+1] -> ds_read frags(g+1) into R-set
//      -> 16 MFMA consuming C-set. All buffer indices compile-time.
#define TAP(P, NW, DOA, DOX, XBW, XBR, DORD, CAf, CBv, RAf, RBv)               \
  {                                                                            \
    asm volatile("s_waitcnt vmcnt(%0)" :: "i"(NW) : "memory");                 \
    asm volatile("s_barrier" ::: "memory");                                    \
    if (DOA) {                                                                 \
      __hip_bfloat16* ab = As + ((P) % 3) * ABUF;                              \
      const int aofs = (((P) + 3) % 9) * CIN + (c + ((P) + 3) / 9) * 32;       \
      g2l16(ab + dstA0, srcA0 + aofs);                                         \
      g2l16(ab + dstA1, srcA1 + aofs);                                         \
    }                                                                          \
    if (DOX) g2l16(xs + (XBW) * XSZ + dstX[(P) < 6 ? (P) : 0],                 \
                   srcX[(P) < 6 ? (P) : 0] + (c + 1) * 32);                    \
    if (DORD) {                                                                \
      const __hip_bfloat16* ar = As + (((P) + 1) % 3) * ABUF;                  \
      const __hip_bfloat16* br = xs + (XBR) * XSZ                              \
                                 + ((((P) + 1) % 9) / 3) * (130 * 32);         \
      _Pragma("unroll")                                                        \
      for (int mi = 0; mi < 4; ++mi) RAf[mi] = *(const bf16x8*)(ar + aOff[mi]);\
      _Pragma("unroll")                                                        \
      for (int ni = 0; ni < 4; ++ni)                                           \
          RBv[ni] = *(const bf16x8*)(br + bOff[ni][(((P) + 1) % 9) % 3]);      \
    }                                                                          \
    __builtin_amdgcn_s_setprio(1);                                             \
    _Pragma("unroll")                                                          \
    for (int mi = 0; mi < 4; ++mi)                                             \
      _Pragma("unroll")                                                        \
      for (int ni = 0; ni < 4; ++ni)                                           \
        acc[mi][ni] = __builtin_amdgcn_mfma_f32_16x16x32_bf16(                 \
            CAf[mi], CBv[ni], acc[mi][ni], 0, 0, 0);                           \
    __builtin_amdgcn_s_setprio(0);                                             \
  }

// even chunks c=0,2,4,6: consume set p%2; X write buf 1, read buf 0 (buf 1 @p8)
#define CHK0(NW0)                                                              \
    TAP(0, NW0, 1, 1, 1, 0, 1, af0, bv0, af1, bv1)                             \
    TAP(1, 3,   1, 1, 1, 0, 1, af1, bv1, af0, bv0)                             \
    TAP(2, 3,   1, 1, 1, 0, 1, af0, bv0, af1, bv1)                             \
    TAP(3, 3,   1, 1, 1, 0, 1, af1, bv1, af0, bv0)                             \
    TAP(4, 3,   1, 1, 1, 0, 1, af0, bv0, af1, bv1)                             \
    TAP(5, 3,   1, 1, 1, 0, 1, af1, bv1, af0, bv0)                             \
    TAP(6, 3,   1, 0, 1, 0, 1, af0, bv0, af1, bv1)                             \
    TAP(7, 2,   1, 0, 1, 0, 1, af1, bv1, af0, bv0)                             \
    TAP(8, 2,   1, 0, 1, 1, 1, af0, bv0, af1, bv1)

// odd chunks c=1,3,5: sets flipped; X write buf 0, read buf 1 (buf 0 @p8)
#define CHK1                                                                   \
    TAP(0, 2, 1, 1, 0, 1, 1, af1, bv1, af0, bv0)                               \
    TAP(1, 3, 1, 1, 0, 1, 1, af0, bv0, af1, bv1)                               \
    TAP(2, 3, 1, 1, 0, 1, 1, af1, bv1, af0, bv0)                               \
    TAP(3, 3, 1, 1, 0, 1, 1, af0, bv0, af1, bv1)                               \
    TAP(4, 3, 1, 1, 0, 1, 1, af1, bv1, af0, bv0)                               \
    TAP(5, 3, 1, 1, 0, 1, 1, af0, bv0, af1, bv1)                               \
    TAP(6, 3, 1, 0, 0, 1, 1, af1, bv1, af0, bv0)                               \
    TAP(7, 2, 1, 0, 0, 1, 1, af0, bv0, af1, bv1)                               \
    TAP(8, 2, 1, 0, 0, 0, 1, af1, bv1, af0, bv0)

// tail chunk c=7 (odd parity): A only while g+3 <= 71 (taps 0..5), no X
#define CHKT                                                                   \
    TAP(0, 2, 1, 0, 0, 1, 1, af1, bv1, af0, bv0)                               \
    TAP(1, 2, 1, 0, 0, 1, 1, af0, bv0, af1, bv1)                               \
    TAP(2, 2, 1, 0, 0, 1, 1, af1, bv1, af0, bv0)                               \
    TAP(3, 2, 1, 0, 0, 1, 1, af0, bv0, af1, bv1)                               \
    TAP(4, 2, 1, 0, 0, 1, 1, af1, bv1, af0, bv0)                               \
    TAP(5, 2, 1, 0, 0, 1, 1, af0, bv0, af1, bv1)                               \
    TAP(6, 2, 0, 0, 0, 1, 1, af1, bv1, af0, bv0)                               \
    TAP(7, 0, 0, 0, 0, 1, 1, af0, bv0, af1, bv1)                               \
    TAP(8, 0, 0, 0, 0, 1, 0, af1, bv1, af0, bv0)

    { const int c = 0; CHK0(0) }
    { const int c = 1; CHK1 }
    { const int c = 2; CHK0(2) }
    { const int c = 3; CHK1 }
    { const int c = 4; CHK0(2) }
    { const int c = 5; CHK1 }
    { const int c = 6; CHK0(2) }
    { const int c = 7; CHKT }

#undef TAP
#undef CHK0
#undef CHK1
#undef CHKT

    // epilogue: max over 8 rotations (4 regs + quarter-swap), write fp32
    const int oBase = (m0 + wm * 64) >> 3;
    #pragma unroll
    for (int mi = 0; mi < 4; ++mi) {
        #pragma unroll
        for (int ni = 0; ni < 4; ++ni) {
            f32x4 a4 = acc[mi][ni];
            float v = fmaxf(fmaxf(a4[0], a4[1]), fmaxf(a4[2], a4[3]));
            v = fmaxf(v, __shfl_xor(v, 16));
            if ((q & 1) == 0) {
                int o = oBase + mi * 2 + (q >> 1);
                int colc = wn * 64 + ni * 16 + lr;
                out[(((size_t)(b * COUT + o)) * HH + y0) * WW + colc] = v;
            }
        }
    }
}

// ===========================================================================
// Fallback fp32 path (round-0, known-correct) in case ws is too small.
// ===========================================================================
__global__ void rotate_weights_kernel(const float* __restrict__ w,
                                      float* __restrict__ rw,
                                      int r0, int rcount) {
    int idx = blockIdx.x * blockDim.x + threadIdx.x;
    int total = COUT * CIN * rcount;
    if (idx >= total) return;
    int rr = idx % rcount;
    int ii = (idx / rcount) % CIN;
    int oo = idx / (rcount * CIN);
    int r  = r0 + rr;
    float ang = 6.283185307179586f * (float)r / 8.0f;
    float cs = cosf(ang), sn = sinf(ang);
    const float* wp = w  + ((size_t)oo * CIN + ii) * 9;
    float*       op = rw + (((size_t)oo * CIN + ii) * rcount + rr) * 9;
    #pragma unroll
    for (int ky = 0; ky < 3; ++ky)
        #pragma unroll
        for (int kx = 0; kx < 3; ++kx) {
            float yg = (2.0f * ky + 1.0f) / 3.0f - 1.0f;
            float xg = (2.0f * kx + 1.0f) / 3.0f - 1.0f;
            float xsf = cs * xg - sn * yg;
            float ysf = sn * xg + cs * yg;
            float ix = ((xsf + 1.0f) * 3.0f - 1.0f) * 0.5f;
            float iy = ((ysf + 1.0f) * 3.0f - 1.0f) * 0.5f;
            float ix0f = floorf(ix), iy0f = floorf(iy);
            float wx1 = ix - ix0f,  wy1 = iy - iy0f;
            float wx0 = 1.0f - wx1, wy0 = 1.0f - wy1;
            int ix0 = (int)ix0f, iy0 = (int)iy0f;
            int ix1 = ix0 + 1,   iy1 = iy0 + 1;
            float acc = 0.0f;
            if (iy0 >= 0 && iy0 < 3 && ix0 >= 0 && ix0 < 3) acc += wp[iy0*3+ix0]*(wy0*wx0);
            if (iy0 >= 0 && iy0 < 3 && ix1 >= 0 && ix1 < 3) acc += wp[iy0*3+ix1]*(wy0*wx1);
            if (iy1 >= 0 && iy1 < 3 && ix0 >= 0 && ix0 < 3) acc += wp[iy1*3+ix0]*(wy1*wx0);
            if (iy1 >= 0 && iy1 < 3 && ix1 >= 0 && ix1 < 3) acc += wp[iy1*3+ix1]*(wy1*wx1);
            op[ky * 3 + kx] = acc;
        }
}

template <int RCOUNT>
__global__ __launch_bounds__(256)
void rotconv_max_kernel(const float* __restrict__ x,
                        const float* __restrict__ rw,
                        float* __restrict__ out,
                        int first) {
    const int tid = threadIdx.x;
    const int tx = tid & 15;
    const int ty = tid >> 4;
    const int x0 = blockIdx.x * 32;
    const int y0 = blockIdx.y * 32;
    const int o  = blockIdx.z % COUT;
    const int b  = blockIdx.z / COUT;
    __shared__ float xsm[34][36];
    float acc[RCOUNT][2][2];
    #pragma unroll
    for (int r = 0; r < RCOUNT; ++r)
        #pragma unroll
        for (int py = 0; py < 2; ++py)
            #pragma unroll
            for (int px = 0; px < 2; ++px) acc[r][py][px] = 0.0f;
    for (int i = 0; i < CIN; ++i) {
        __syncthreads();
        const float* xp = x + ((size_t)(b * CIN + i)) * (HH * WW);
        for (int idx = tid; idx < 34 * 34; idx += 256) {
            int row = idx / 34, col = idx - row * 34;
            int gy = y0 - 1 + row, gx = x0 - 1 + col;
            float v = 0.0f;
            if (gy >= 0 && gy < HH && gx >= 0 && gx < WW) v = xp[gy * WW + gx];
            xsm[row][col] = v;
        }
        __syncthreads();
        float xv[4][4];
        #pragma unroll
        for (int ry = 0; ry < 4; ++ry)
            #pragma unroll
            for (int cx = 0; cx < 4; ++cx) xv[ry][cx] = xsm[ty*2+ry][tx*2+cx];
        const float* wp = rw + ((size_t)(o * CIN + i)) * (RCOUNT * 9);
        #pragma unroll
        for (int r = 0; r < RCOUNT; ++r) {
            float wv[9];
            #pragma unroll
            for (int t2 = 0; t2 < 9; ++t2) wv[t2] = wp[r * 9 + t2];
            #pragma unroll
            for (int py = 0; py < 2; ++py)
                #pragma unroll
                for (int px = 0; px < 2; ++px) {
                    float a = acc[r][py][px];
                    #pragma unroll
                    for (int ky = 0; ky < 3; ++ky)
                        #pragma unroll
                        for (int kx = 0; kx < 3; ++kx)
                            a += xv[py+ky][px+kx] * wv[ky*3+kx];
                    acc[r][py][px] = a;
                }
        }
    }
    #pragma unroll
    for (int py = 0; py < 2; ++py)
        #pragma unroll
        for (int px = 0; px < 2; ++px) {
            float m = acc[0][py][px];
            #pragma unroll
            for (int r = 1; r < RCOUNT; ++r) m = fmaxf(m, acc[r][py][px]);
            int oy = y0 + ty * 2 + py;
            int ox = x0 + tx * 2 + px;
            float* op = out + (((size_t)(b * COUT + o)) * HH + oy) * WW + ox;
            if (first) *op = m;
            else       *op = fmaxf(*op, m);
        }
}

// ===========================================================================
extern "C" void kernel_launch(void* const* d_in, const int* in_sizes, int n_in,
                              void* d_out, int out_size, void* d_ws, size_t ws_size,
                              hipStream_t stream) {
    const float* x = (const float*)d_in[0];
    const float* w = (const float*)d_in[1];
    float* out = (float*)d_out;

    const size_t xbBytes = ((size_t)BB * HH * WW + WW) * CIN * sizeof(__hip_bfloat16); // +1 zero row
    const size_t rwBytes = (size_t)MTOT * KTAPS * CIN * sizeof(__hip_bfloat16);

    if (ws_size >= xbBytes + rwBytes) {
        __hip_bfloat16* xbuf = (__hip_bfloat16*)d_ws;
        __hip_bfloat16* rwb  = (__hip_bfloat16*)((char*)d_ws + xbBytes);

        to_nhwc_bf16<<<dim3((HH * WW) / 32, CIN / 32, BB), 256, 0, stream>>>(x, xbuf);
        zero_guard_row<<<(WW * CIN) / 256, 256, 0, stream>>>(xbuf);
        rotate_weights_bf16<<<MTOT, 256, 0, stream>>>(w, rwb);
        rotconv_mfma_kernel<<<8192, 256, 0, stream>>>(xbuf, rwb, out);
        return;
    }

    // ---- fallback fp32 path ----
    float* rw = (float*)d_ws;
    int chunk = 8;
    while (chunk > 1 && (size_t)COUT * CIN * chunk * 9 * sizeof(float) > ws_size)
        chunk >>= 1;
    int first = 1;
    for (int r0 = 0; r0 < R_TOTAL; r0 += chunk) {
        int rc = chunk;
        int total = COUT * CIN * rc;
        rotate_weights_kernel<<<(total + 255) / 256, 256, 0, stream>>>(w, rw, r0, rc);
        dim3 grid(WW / 32, HH / 32, BB * COUT);
        switch (rc) {
            case 8: rotconv_max_kernel<8><<<grid, 256, 0, stream>>>(x, rw, out, first); break;
            case 4: rotconv_max_kernel<4><<<grid, 256, 0, stream>>>(x, rw, out, first); break;
            case 2: rotconv_max_kernel<2><<<grid, 256, 0, stream>>>(x, rw, out, first); break;
            default: rotconv_max_kernel<1><<<grid, 256, 0, stream>>>(x, rw, out, first); break;
        }
        first = 0;
    }
}

// Round 13
// 510.122 us; speedup vs baseline: 1.6695x; 1.2908x over previous
//
#include <hip/hip_runtime.h>
#include <hip/hip_bf16.h>
#include <math.h>

typedef __attribute__((ext_vector_type(8))) short bf16x8;
typedef __attribute__((ext_vector_type(4))) float f32x4;

#define R_TOTAL 8
#define CIN     256
#define COUT    256
#define HH      128
#define WW      128
#define BB      4
#define MTOT    (COUT * R_TOTAL)   // 2048
#define KTAPS   9

#define ROWSZ 4160                 // one X row slot: 130 cols x 32 ch (elems)
#define ABUF  (128 * 32)           // 4096 elems per A buffer (8 KB)

// ---------------------------------------------------------------------------
// async global->LDS, 16B per lane (lane l lands at base + l*16).
// ---------------------------------------------------------------------------
__device__ __forceinline__ void g2l16(void* lds, const void* g) {
    __builtin_amdgcn_global_load_lds(
        (const __attribute__((address_space(1))) unsigned int*)g,
        (__attribute__((address_space(3))) unsigned int*)lds,
        16, 0, 0);
}

// ---------------------------------------------------------------------------
// x (B,C,H,W) fp32 -> xb (B,H,W,C) bf16 (+ one appended zero row).
// ---------------------------------------------------------------------------
__global__ __launch_bounds__(256)
void to_nhwc_bf16(const float* __restrict__ x, __hip_bfloat16* __restrict__ xb) {
    __shared__ __hip_bfloat16 t[32][33];
    const int b  = blockIdx.z;
    const int c0 = blockIdx.y * 32;
    const int p0 = blockIdx.x * 32;
    const int tx = threadIdx.x & 31;
    const int ty = threadIdx.x >> 5;
    const float* xp = x + (size_t)b * CIN * (HH * WW);
    #pragma unroll
    for (int j = 0; j < 4; ++j) {
        int c = ty * 4 + j;
        t[c][tx] = __float2bfloat16(xp[(size_t)(c0 + c) * (HH * WW) + p0 + tx]);
    }
    __syncthreads();
    __hip_bfloat16* op = xb + ((size_t)b * (HH * WW) + p0) * CIN + c0;
    #pragma unroll
    for (int j = 0; j < 4; ++j) {
        int p = ty * 4 + j;
        op[(size_t)p * CIN + tx] = t[tx][p];
    }
}

__global__ __launch_bounds__(256)
void zero_guard_row(__hip_bfloat16* __restrict__ xb) {
    size_t base = (size_t)BB * HH * WW * CIN;
    int i = blockIdx.x * 256 + threadIdx.x;
    xb[base + i] = __float2bfloat16(0.0f);
}

// ---------------------------------------------------------------------------
// Rotate weights (fp32 math == jax affine_grid/grid_sample, align_corners=F,
// zero pad) -> rwb[m][tap][i] bf16, m = o*8 + r.
// ---------------------------------------------------------------------------
__global__ __launch_bounds__(256)
void rotate_weights_bf16(const float* __restrict__ w, __hip_bfloat16* __restrict__ rwb) {
    const int i = threadIdx.x;
    const int m = blockIdx.x;
    const int o = m >> 3, r = m & 7;

    float ang = 6.283185307179586f * (float)r / 8.0f;
    float cs = cosf(ang), sn = sinf(ang);

    const float* wp = w + ((size_t)o * CIN + i) * 9;
    __hip_bfloat16* op = rwb + (size_t)m * (KTAPS * CIN) + i;

    #pragma unroll
    for (int ky = 0; ky < 3; ++ky) {
        #pragma unroll
        for (int kx = 0; kx < 3; ++kx) {
            float yg = (2.0f * (float)ky + 1.0f) / 3.0f - 1.0f;
            float xg = (2.0f * (float)kx + 1.0f) / 3.0f - 1.0f;
            float xsf = cs * xg - sn * yg;
            float ysf = sn * xg + cs * yg;
            float ix = ((xsf + 1.0f) * 3.0f - 1.0f) * 0.5f;
            float iy = ((ysf + 1.0f) * 3.0f - 1.0f) * 0.5f;
            float ix0f = floorf(ix), iy0f = floorf(iy);
            float wx1 = ix - ix0f,  wy1 = iy - iy0f;
            float wx0 = 1.0f - wx1, wy0 = 1.0f - wy1;
            int ix0 = (int)ix0f, iy0 = (int)iy0f;
            int ix1 = ix0 + 1,   iy1 = iy0 + 1;
            float acc = 0.0f;
            if (iy0 >= 0 && iy0 < 3 && ix0 >= 0 && ix0 < 3) acc += wp[iy0*3+ix0] * (wy0*wx0);
            if (iy0 >= 0 && iy0 < 3 && ix1 >= 0 && ix1 < 3) acc += wp[iy0*3+ix1] * (wy0*wx1);
            if (iy1 >= 0 && iy1 < 3 && ix0 >= 0 && ix0 < 3) acc += wp[iy1*3+ix0] * (wy1*wx0);
            if (iy1 >= 0 && iy1 < 3 && ix1 >= 0 && ix1 < 3) acc += wp[iy1*3+ix1] * (wy1*wx1);
            op[(ky * 3 + kx) * CIN] = __float2bfloat16(acc);
        }
    }
}

// ---------------------------------------------------------------------------
// Main MFMA conv: 256 threads = 4 waves (2M x 2N), block tile 128M x 256N
// (TWO image rows; wave tile 64M x 128N -> 42.7 FLOP/LDS-byte).
// K = 8 chunks(32ch) x 9 taps (t = 9c+p).
// Issue-early tap: stage A(t+2) [+ one X row part] -> counted vmcnt -> raw
// s_barrier -> ds_read frags -> 32 MFMA.
// WAR-safe buffering (R12's race fix):
//  - A: FOUR slots, slot(t) = t%4. Write at tap t targets slot (t+2)%4 whose
//    old content A(t-2) was read at tap t-2 -> done before barrier(t-1) <
//    issue point. Slot index (c+p)%4 -> chunks fully unrolled with literal C.
//  - X: rolling 5-slot row buffer, slot(r,c) = (4c+r)%5. row3@c staged at
//    taps 1-2 (NOT 0); rows 0-2 of c+1 at taps 3-8. Every X write is >=1 full
//    barrier after the last read of the slot's old content (verified).
// NW tables FIFO-derived: c0 [2,4,4,5,6,7,7,7,7]; steady [6,6,6,7,7,7,7,7,7];
// tail [6,6,6,6,5,4,4,2,0]. LDS 72.6 KB -> 2 blocks/CU (8 waves, 2/SIMD).
// ---------------------------------------------------------------------------
__global__ __launch_bounds__(256, 2)
void rotconv_mfma_kernel(const __hip_bfloat16* __restrict__ xb,
                         const __hip_bfloat16* __restrict__ rwb,
                         float* __restrict__ out) {
    const int tid  = threadIdx.x;
    const int lane = tid & 63;
    const int w    = tid >> 6;        // 0..3
    const int wm   = w >> 1;          // 0..1
    const int wn   = w & 1;           // 0..1  (owns output row y0+wn)
    const int q    = lane >> 4, lr = lane & 15;

    // bijective XCD swizzle (4096 % 8 == 0), m-major for A-panel L2 reuse
    const int bid = (blockIdx.x & 7) * 512 + (blockIdx.x >> 3);
    const int mt  = bid >> 8;         // 0..15
    const int nt  = bid & 255;        // 0..255
    const int b   = nt >> 6;          // 0..3
    const int y0  = (nt & 63) * 2;    // 0..126
    const int m0  = mt << 7;

    __shared__ __align__(16) __hip_bfloat16 xs[5 * ROWSZ];
    __shared__ __align__(16) __hip_bfloat16 As[4 * ABUF];

    // zero halo columns (colL = 0 and 129) of all 5 slots (stay zero forever)
    for (int j = tid; j < 5 * 64; j += 256) {
        int slot = j >> 6;
        int rem  = j & 63;
        int colL = (rem >> 5) ? 129 : 0;
        int ch   = rem & 31;
        xs[slot * ROWSZ + colL * 32 + ch] = __float2bfloat16(0.0f);
    }

    // ---- A read offset (single reg; rows step by 16 -> swizzle invariant) --
    const int arow_r = wm * 64 + lr;
    const int aOff0  = arow_r * 32 + 8 * (q ^ ((arow_r >> 1) & 3));
    // ---- B read offsets: colL = lr + kx (ni*16 -> imm; swizzle inv mod 16) -
    int bOff0[3];
    #pragma unroll
    for (int kx = 0; kx < 3; ++kx) {
        int colL = lr + kx;
        bOff0[kx] = colL * 32 + 8 * (q ^ ((colL >> 1) & 3));
    }

    // ---- A staging: wave w covers rows w*32..w*32+31 (2 g2l per wave) ----
    const int arow0 = w * 32 + (lane >> 2);
    const int arow1 = arow0 + 16;
    const int dstA0 = (w * 32) * 32;                    // wave-uniform
    const int dstA1 = (w * 32 + 16) * 32;
    const int voffA0 = (m0 + arow0) * (KTAPS * CIN) + 8 * ((lane & 3) ^ ((arow0 >> 1) & 3));
    const int voffA1 = (m0 + arow1) * (KTAPS * CIN) + 8 * ((lane & 3) ^ ((arow1 >> 1) & 3));

    // ---- X staging: 4 window rows x 2 col-parts/wave ----
    // part0 cols w*16.., part1 cols (w+4)*16..; +64 cols keeps swizzle (64%4==0)
    int rowOff[4];                                      // wave-uniform -> SGPR
    #pragma unroll
    for (int r = 0; r < 4; ++r) {
        int gy = y0 - 1 + r;
        int rowIdx = ((unsigned)gy < (unsigned)HH) ? (b * HH + gy) : (BB * HH);
        rowOff[r] = rowIdx * (WW * CIN);
    }
    const int gx0   = w * 16 + (lane >> 2);
    const int voffX = gx0 * CIN + 8 * ((lane & 3) ^ (((gx0 + 1) >> 1) & 3));
    const int dstXp0 = 32 + w * 512;                    // elem offset in slot
    const int dstXp1 = 32 + (w + 4) * 512;

    f32x4 acc[4][8];
    #pragma unroll
    for (int mi = 0; mi < 4; ++mi)
        #pragma unroll
        for (int ni = 0; ni < 8; ++ni) {
            f32x4 z = {0.f, 0.f, 0.f, 0.f};
            acc[mi][ni] = z;
        }

    __syncthreads();   // halo zeros visible

    // prologue: X rows r0..r3 -> slots 0..3 (chunk 0); A(0)->s0, A(1)->s1
    #pragma unroll
    for (int r = 0; r < 4; ++r) {
        g2l16(xs + r * ROWSZ + dstXp0, xb + rowOff[r] + voffX);
        g2l16(xs + r * ROWSZ + dstXp1, xb + rowOff[r] + voffX + 64 * CIN);
    }
    g2l16(As + dstA0, rwb + voffA0);
    g2l16(As + dstA1, rwb + voffA1);
    g2l16(As + ABUF + dstA0, rwb + voffA0 + CIN);
    g2l16(As + ABUF + dstA1, rwb + voffA1 + CIN);
    asm volatile("s_waitcnt vmcnt(0)" ::: "memory");
    __syncthreads();

#define WRAP5(v) ((v) >= 5 ? (v) - 5 : (v))

// ---- one tap (literal chunk C, tap P): issue A(t+2) into slot (C+P+2)&3
//      [+ one X row part] -> counted wait -> barrier -> ds_read A slot
//      (C+P)&3 + B row -> 32 MFMA in 2 half-clusters.
#define TAP(C, P, NW, DOA, DOX, XIDX, XSLOT, XOFF)                             \
  {                                                                            \
    if (DOA) {                                                                 \
      __hip_bfloat16* ab = As + (((C) + (P) + 2) & 3) * ABUF;                  \
      const int aofs = (((P) + 2) % 9) * CIN + ((((P) + 2) / 9) + (C)) * 32;   \
      g2l16(ab + dstA0, rwb + voffA0 + aofs);                                  \
      g2l16(ab + dstA1, rwb + voffA1 + aofs);                                  \
    }                                                                          \
    if (DOX) {                                                                 \
      g2l16(xs + (XSLOT) * ROWSZ + (((XIDX) & 1) ? dstXp1 : dstXp0),           \
            xb + rowOff[(XIDX) >> 1] + voffX + ((XIDX) & 1) * (64 * CIN)       \
               + (XOFF));                                                      \
    }                                                                          \
    asm volatile("s_waitcnt vmcnt(%0)" :: "i"(NW) : "memory");                 \
    asm volatile("s_barrier" ::: "memory");                                    \
    {                                                                          \
      const __hip_bfloat16* ar = As + (((C) + (P)) & 3) * ABUF + aOff0;        \
      const __hip_bfloat16* br =                                               \
          ((P) / 3 == 0 ? xrow0 : (P) / 3 == 1 ? xrow1 : xrow2)                \
          + bOff0[(P) % 3];                                                    \
      bf16x8 af[4];                                                            \
      _Pragma("unroll")                                                        \
      for (int mi = 0; mi < 4; ++mi) af[mi] = *(const bf16x8*)(ar + mi * 512); \
      _Pragma("unroll")                                                        \
      for (int h = 0; h < 2; ++h) {                                            \
        bf16x8 bv[4];                                                          \
        _Pragma("unroll")                                                      \
        for (int nj = 0; nj < 4; ++nj)                                         \
            bv[nj] = *(const bf16x8*)(br + (h * 4 + nj) * 512);                \
        __builtin_amdgcn_s_setprio(1);                                         \
        _Pragma("unroll")                                                      \
        for (int mi = 0; mi < 4; ++mi)                                         \
          _Pragma("unroll")                                                    \
          for (int nj = 0; nj < 4; ++nj)                                       \
            acc[mi][h * 4 + nj] = __builtin_amdgcn_mfma_f32_16x16x32_bf16(     \
                af[mi], bv[nj], acc[mi][h * 4 + nj], 0, 0, 0);                 \
        __builtin_amdgcn_s_setprio(0);                                         \
      }                                                                        \
    }                                                                          \
  }

#define CHUNK_HDR(C)                                                           \
    const int rbw = ((4 * (C)) % 5) + wn;                                      \
    const __hip_bfloat16* xrow0 = xs + WRAP5(rbw) * ROWSZ;                     \
    const __hip_bfloat16* xrow1 = xs + WRAP5(rbw + 1) * ROWSZ;                 \
    const __hip_bfloat16* xrow2 = xs + WRAP5(rbw + 2) * ROWSZ;

// steady chunk C=1..6: X row3@C at taps 1-2 (slot (4C+3)%5), rows 0-2 of C+1
// at taps 3-8 (slots (4C+4)%5, (4C)%5, (4C+1)%5). NW [6,6,6,7,7,7,7,7,7].
#define CHK_MID(C)                                                             \
  { CHUNK_HDR(C)                                                               \
    TAP(C, 0, 6, 1, 0, 0, 0, 0)                                                \
    TAP(C, 1, 6, 1, 1, 6, (4*(C)+3)%5, (C)*32)                                 \
    TAP(C, 2, 6, 1, 1, 7, (4*(C)+3)%5, (C)*32)                                 \
    TAP(C, 3, 7, 1, 1, 0, (4*(C)+4)%5, ((C)+1)*32)                             \
    TAP(C, 4, 7, 1, 1, 1, (4*(C)+4)%5, ((C)+1)*32)                             \
    TAP(C, 5, 7, 1, 1, 2, (4*(C))%5,   ((C)+1)*32)                             \
    TAP(C, 6, 7, 1, 1, 3, (4*(C))%5,   ((C)+1)*32)                             \
    TAP(C, 7, 7, 1, 1, 4, (4*(C)+1)%5, ((C)+1)*32)                             \
    TAP(C, 8, 7, 1, 1, 5, (4*(C)+1)%5, ((C)+1)*32)                             \
  }

    // ---- chunk 0: rows 0-3 prologue-staged; stage rows 0-2 of c1 at taps 3-8
    { CHUNK_HDR(0)
      TAP(0, 0, 2, 1, 0, 0, 0, 0)
      TAP(0, 1, 4, 1, 0, 0, 0, 0)
      TAP(0, 2, 4, 1, 0, 0, 0, 0)
      TAP(0, 3, 5, 1, 1, 0, 4, 32)
      TAP(0, 4, 6, 1, 1, 1, 4, 32)
      TAP(0, 5, 7, 1, 1, 2, 0, 32)
      TAP(0, 6, 7, 1, 1, 3, 0, 32)
      TAP(0, 7, 7, 1, 1, 4, 1, 32)
      TAP(0, 8, 7, 1, 1, 5, 1, 32)
    }

    CHK_MID(1) CHK_MID(2) CHK_MID(3) CHK_MID(4) CHK_MID(5) CHK_MID(6)

    // ---- tail chunk 7: row3@c7 at taps 1-2 (slot (31)%5=1); A while t+2<=71
    { CHUNK_HDR(7)
      TAP(7, 0, 6, 1, 0, 0, 0, 0)
      TAP(7, 1, 6, 1, 1, 6, 1, 224)
      TAP(7, 2, 6, 1, 1, 7, 1, 224)
      TAP(7, 3, 6, 1, 0, 0, 0, 0)
      TAP(7, 4, 5, 1, 0, 0, 0, 0)
      TAP(7, 5, 4, 1, 0, 0, 0, 0)
      TAP(7, 6, 4, 1, 0, 0, 0, 0)
      TAP(7, 7, 2, 0, 0, 0, 0, 0)
      TAP(7, 8, 0, 0, 0, 0, 0, 0)
    }

#undef TAP
#undef CHK_MID
#undef CHUNK_HDR
#undef WRAP5

    // epilogue: max over 8 rotations (4 regs + quarter-swap), write fp32
    const int oBase = (m0 + wm * 64) >> 3;
    const int yOut  = y0 + wn;
    #pragma unroll
    for (int mi = 0; mi < 4; ++mi) {
        #pragma unroll
        for (int ni = 0; ni < 8; ++ni) {
            f32x4 a4 = acc[mi][ni];
            float v = fmaxf(fmaxf(a4[0], a4[1]), fmaxf(a4[2], a4[3]));
            v = fmaxf(v, __shfl_xor(v, 16));
            if ((q & 1) == 0) {
                int o = oBase + mi * 2 + (q >> 1);
                int colc = ni * 16 + lr;
                out[(((size_t)(b * COUT + o)) * HH + yOut) * WW + colc] = v;
            }
        }
    }
}

// ===========================================================================
// Fallback fp32 path (round-0, known-correct) in case ws is too small.
// ===========================================================================
__global__ void rotate_weights_kernel(const float* __restrict__ w,
                                      float* __restrict__ rw,
                                      int r0, int rcount) {
    int idx = blockIdx.x * blockDim.x + threadIdx.x;
    int total = COUT * CIN * rcount;
    if (idx >= total) return;
    int rr = idx % rcount;
    int ii = (idx / rcount) % CIN;
    int oo = idx / (rcount * CIN);
    int r  = r0 + rr;
    float ang = 6.283185307179586f * (float)r / 8.0f;
    float cs = cosf(ang), sn = sinf(ang);
    const float* wp = w  + ((size_t)oo * CIN + ii) * 9;
    float*       op = rw + (((size_t)oo * CIN + ii) * rcount + rr) * 9;
    #pragma unroll
    for (int ky = 0; ky < 3; ++ky)
        #pragma unroll
        for (int kx = 0; kx < 3; ++kx) {
            float yg = (2.0f * ky + 1.0f) / 3.0f - 1.0f;
            float xg = (2.0f * kx + 1.0f) / 3.0f - 1.0f;
            float xsf = cs * xg - sn * yg;
            float ysf = sn * xg + cs * yg;
            float ix = ((xsf + 1.0f) * 3.0f - 1.0f) * 0.5f;
            float iy = ((ysf + 1.0f) * 3.0f - 1.0f) * 0.5f;
            float ix0f = floorf(ix), iy0f = floorf(iy);
            float wx1 = ix - ix0f,  wy1 = iy - iy0f;
            float wx0 = 1.0f - wx1, wy0 = 1.0f - wy1;
            int ix0 = (int)ix0f, iy0 = (int)iy0f;
            int ix1 = ix0 + 1,   iy1 = iy0 + 1;
            float acc = 0.0f;
            if (iy0 >= 0 && iy0 < 3 && ix0 >= 0 && ix0 < 3) acc += wp[iy0*3+ix0]*(wy0*wx0);
            if (iy0 >= 0 && iy0 < 3 && ix1 >= 0 && ix1 < 3) acc += wp[iy0*3+ix1]*(wy0*wx1);
            if (iy1 >= 0 && iy1 < 3 && ix0 >= 0 && ix0 < 3) acc += wp[iy1*3+ix0]*(wy1*wx0);
            if (iy1 >= 0 && iy1 < 3 && ix1 >= 0 && ix1 < 3) acc += wp[iy1*3+ix1]*(wy1*wx1);
            op[ky * 3 + kx] = acc;
        }
}

template <int RCOUNT>
__global__ __launch_bounds__(256)
void rotconv_max_kernel(const float* __restrict__ x,
                        const float* __restrict__ rw,
                        float* __restrict__ out,
                        int first) {
    const int tid = threadIdx.x;
    const int tx = tid & 15;
    const int ty = tid >> 4;
    const int x0 = blockIdx.x * 32;
    const int y0 = blockIdx.y * 32;
    const int o  = blockIdx.z % COUT;
    const int b  = blockIdx.z / COUT;
    __shared__ float xsm[34][36];
    float acc[RCOUNT][2][2];
    #pragma unroll
    for (int r = 0; r < RCOUNT; ++r)
        #pragma unroll
        for (int py = 0; py < 2; ++py)
            #pragma unroll
            for (int px = 0; px < 2; ++px) acc[r][py][px] = 0.0f;
    for (int i = 0; i < CIN; ++i) {
        __syncthreads();
        const float* xp = x + ((size_t)(b * CIN + i)) * (HH * WW);
        for (int idx = tid; idx < 34 * 34; idx += 256) {
            int row = idx / 34, col = idx - row * 34;
            int gy = y0 - 1 + row, gx = x0 - 1 + col;
            float v = 0.0f;
            if (gy >= 0 && gy < HH && gx >= 0 && gx < WW) v = xp[gy * WW + gx];
            xsm[row][col] = v;
        }
        __syncthreads();
        float xv[4][4];
        #pragma unroll
        for (int ry = 0; ry < 4; ++ry)
            #pragma unroll
            for (int cx = 0; cx < 4; ++cx) xv[ry][cx] = xsm[ty*2+ry][tx*2+cx];
        const float* wp = rw + ((size_t)(o * CIN + i)) * (RCOUNT * 9);
        #pragma unroll
        for (int r = 0; r < RCOUNT; ++r) {
            float wv[9];
            #pragma unroll
            for (int t2 = 0; t2 < 9; ++t2) wv[t2] = wp[r * 9 + t2];
            #pragma unroll
            for (int py = 0; py < 2; ++py)
                #pragma unroll
                for (int px = 0; px < 2; ++px) {
                    float a = acc[r][py][px];
                    #pragma unroll
                    for (int ky = 0; ky < 3; ++ky)
                        #pragma unroll
                        for (int kx = 0; kx < 3; ++kx)
                            a += xv[py+ky][px+kx] * wv[ky*3+kx];
                    acc[r][py][px] = a;
                }
        }
    }
    #pragma unroll
    for (int py = 0; py < 2; ++py)
        #pragma unroll
        for (int px = 0; px < 2; ++px) {
            float m = acc[0][py][px];
            #pragma unroll
            for (int r = 1; r < RCOUNT; ++r) m = fmaxf(m, acc[r][py][px]);
            int oy = y0 + ty * 2 + py;
            int ox = x0 + tx * 2 + px;
            float* op = out + (((size_t)(b * COUT + o)) * HH + oy) * WW + ox;
            if (first) *op = m;
            else       *op = fmaxf(*op, m);
        }
}

// ===========================================================================
extern "C" void kernel_launch(void* const* d_in, const int* in_sizes, int n_in,
                              void* d_out, int out_size, void* d_ws, size_t ws_size,
                              hipStream_t stream) {
    const float* x = (const float*)d_in[0];
    const float* w = (const float*)d_in[1];
    float* out = (float*)d_out;

    const size_t xbBytes = ((size_t)BB * HH * WW + WW) * CIN * sizeof(__hip_bfloat16); // +1 zero row
    const size_t rwBytes = (size_t)MTOT * KTAPS * CIN * sizeof(__hip_bfloat16);

    if (ws_size >= xbBytes + rwBytes) {
        __hip_bfloat16* xbuf = (__hip_bfloat16*)d_ws;
        __hip_bfloat16* rwb  = (__hip_bfloat16*)((char*)d_ws + xbBytes);

        to_nhwc_bf16<<<dim3((HH * WW) / 32, CIN / 32, BB), 256, 0, stream>>>(x, xbuf);
        zero_guard_row<<<(WW * CIN) / 256, 256, 0, stream>>>(xbuf);
        rotate_weights_bf16<<<MTOT, 256, 0, stream>>>(w, rwb);
        rotconv_mfma_kernel<<<4096, 256, 0, stream>>>(xbuf, rwb, out);
        return;
    }

    // ---- fallback fp32 path ----
    float* rw = (float*)d_ws;
    int chunk = 8;
    while (chunk > 1 && (size_t)COUT * CIN * chunk * 9 * sizeof(float) > ws_size)
        chunk >>= 1;
    int first = 1;
    for (int r0 = 0; r0 < R_TOTAL; r0 += chunk) {
        int rc = chunk;
        int total = COUT * CIN * rc;
        rotate_weights_kernel<<<(total + 255) / 256, 256, 0, stream>>>(w, rw, r0, rc);
        dim3 grid(WW / 32, HH / 32, BB * COUT);
        switch (rc) {
            case 8: rotconv_max_kernel<8><<<grid, 256, 0, stream>>>(x, rw, out, first); break;
            case 4: rotconv_max_kernel<4><<<grid, 256, 0, stream>>>(x, rw, out, first); break;
            case 2: rotconv_max_kernel<2><<<grid, 256, 0, stream>>>(x, rw, out, first); break;
            default: rotconv_max_kernel<1><<<grid, 256, 0, stream>>>(x, rw, out, first); break;
        }
        first = 0;
    }
}